// Round 4
// baseline (42.698 us; speedup 1.0000x reference)
//
#include <hip/hip_runtime.h>
#include <math.h>

#define B 4
#define NP 4096
#define DIM 128
#define CCH 64
#define NS 8

// ========== K1: ball query (1 query/block, 4-wave region split) + transpose ==
// Blocks [0, B*NP): BQ. Each of 4 waves scans a disjoint quarter (16 chunks of
// 64 points) with rank-based parallel deposit + 2-deep prefetch; waves merge
// their region-local first-8 lists in index order. Worst-case serial chain =
// 16 chunks (vs 64 when one wave owns the whole batch).
// Blocks [B*NP, B*NP + B*128): f2 [b][d][n] -> f2T [b][n][d] 32x128 tiles.
__global__ __launch_bounds__(256) void kA_bq_transpose(
    const float* __restrict__ coords, const float* __restrict__ xyz2,
    int* __restrict__ idxb, const float* __restrict__ f2,
    float* __restrict__ o2) {
  int blk = blockIdx.x;
  int t = threadIdx.x;
  __shared__ float tile[128][33];
  __shared__ int sidx[4][NS];
  __shared__ int scnt[4];
  if (blk < B * NP) {
    int b = blk >> 12, m = blk & (NP - 1);
    int wv = t >> 6, lane = t & 63;
    const float* cp = coords + ((size_t)b * NP + m) * 3;
    float cx = cp[0], cy = cp[1], cz = cp[2];
    const float* xz = xyz2 + (size_t)b * NP * 3;
    int base = wv * 1024;
    int j0 = (base + lane) * 3;
    float ax = xz[j0], ay = xz[j0 + 1], az = xz[j0 + 2];
    int j1 = (base + 64 + lane) * 3;
    float bx = xz[j1], by = xz[j1 + 1], bz = xz[j1 + 2];
    int cnt = 0;
#pragma unroll 1
    for (int c = 0; c < 16; c += 2) {
      int c2 = (c + 2 < 16) ? c + 2 : 15;
      int c3 = (c + 3 < 16) ? c + 3 : 15;
      int jn2 = (base + c2 * 64 + lane) * 3;
      int jn3 = (base + c3 * 64 + lane) * 3;
      float nax = xz[jn2], nay = xz[jn2 + 1], naz = xz[jn2 + 2];
      float nbx = xz[jn3], nby = xz[jn3 + 1], nbz = xz[jn3 + 2];
      {
        // no-fma so the d2<1 boundary matches numpy rounding
        float dx = __fsub_rn(cx, ax);
        float dy = __fsub_rn(cy, ay);
        float dz = __fsub_rn(cz, az);
        float d2 = __fadd_rn(__fadd_rn(__fmul_rn(dx, dx), __fmul_rn(dy, dy)),
                             __fmul_rn(dz, dz));
        bool hit = d2 < 1.0f;
        unsigned long long mk = __ballot(hit);
        if (mk) {
          int rank = cnt + __popcll(mk & ((1ull << lane) - 1ull));
          if (hit && rank < NS) sidx[wv][rank] = base + c * 64 + lane;
          cnt += __popcll(mk);
        }
      }
      if (cnt >= NS) break;
      {
        float dx = __fsub_rn(cx, bx);
        float dy = __fsub_rn(cy, by);
        float dz = __fsub_rn(cz, bz);
        float d2 = __fadd_rn(__fadd_rn(__fmul_rn(dx, dx), __fmul_rn(dy, dy)),
                             __fmul_rn(dz, dz));
        bool hit = d2 < 1.0f;
        unsigned long long mk = __ballot(hit);
        if (mk) {
          int rank = cnt + __popcll(mk & ((1ull << lane) - 1ull));
          if (hit && rank < NS) sidx[wv][rank] = base + (c + 1) * 64 + lane;
          cnt += __popcll(mk);
        }
      }
      if (cnt >= NS) break;
      ax = nax; ay = nay; az = naz;
      bx = nbx; by = nby; bz = nbz;
    }
    if (lane == 0) scnt[wv] = (cnt < NS) ? cnt : NS;
    __syncthreads();
    if (t < NS) {
      int c0 = scnt[0], c1 = scnt[1], c2 = scnt[2], c3 = scnt[3];
      int total = c0 + c1 + c2 + c3;
      int v;
      if (t < c0) v = sidx[0][t];
      else if (t < c0 + c1) v = sidx[1][t - c0];
      else if (t < c0 + c1 + c2) v = sidx[2][t - c0 - c1];
      else if (t < total) v = sidx[3][t - c0 - c1 - c2];
      else v = (c0 > 0) ? sidx[0][0]
             : (c1 > 0) ? sidx[1][0]
             : (c2 > 0) ? sidx[2][0]
             : (c3 > 0) ? sidx[3][0] : 0;
      idxb[((size_t)b * NP + m) * NS + t] = v;
    }
  } else {
    int tb = blk - B * NP;
    int b = tb >> 7;
    int n0 = (tb & 127) * 32;
    const float* s = f2 + (size_t)b * DIM * NP;
    float* d = o2 + (size_t)b * NP * DIM;
    int dr = t >> 3;
    int ng = t & 7;
#pragma unroll
    for (int k = 0; k < 4; ++k) {
      int dd = dr + 32 * k;
      float4 v = *(const float4*)&s[(size_t)dd * NP + n0 + ng * 4];
      tile[dd][ng * 4 + 0] = v.x;
      tile[dd][ng * 4 + 1] = v.y;
      tile[dd][ng * 4 + 2] = v.z;
      tile[dd][ng * 4 + 3] = v.w;
    }
    __syncthreads();
    int n = t >> 3;
#pragma unroll
    for (int k = 0; k < 4; ++k) {
      int d0 = (t & 7) * 4 + 32 * k;
      float4 w;
      w.x = tile[d0 + 0][n];
      w.y = tile[d0 + 1][n];
      w.z = tile[d0 + 2][n];
      w.w = tile[d0 + 3][n];
      *(float4*)&d[(size_t)(n0 + n) * DIM + d0] = w;
    }
  }
}

// ========== K2: corr + feat + moment partials (1024 x 256) ===================
// Batched f2T gathers (all 16 rows in flight), feat + 14 moment partials.
__global__ __launch_bounds__(256) void k_corrfeat(
    const float* __restrict__ coords, const float* __restrict__ xyz2,
    const float* __restrict__ f1, const float* __restrict__ f2,
    const float* __restrict__ f2T, const int* __restrict__ idxb,
    float* __restrict__ feat, float* __restrict__ parts, int trans) {
  int blk = blockIdx.x;
  int t = threadIdx.x;
  int bq = (blk & 7) >> 1;
  int chunk = ((blk >> 3) << 1) | (blk & 1);
  int m0 = chunk * 16;
  __shared__ float As[16 * 132];
  __shared__ float red[4][14];

  int g = t >> 3;
  int l = t & 7;
  size_t ibase = ((size_t)bq * NP + m0) * NS;
  // issue idx loads before As staging; they ride out the staging + barrier
  int id0 = idxb[ibase + g], id1 = idxb[ibase + 32 + g];
  int id2 = idxb[ibase + 64 + g], id3 = idxb[ibase + 96 + g];

  if (trans) {
#pragma unroll
    for (int pass = 0; pass < 2; ++pass) {
      int d = pass * 64 + (t >> 2);
      int j4 = t & 3;
      float4 v = *(const float4*)&f1[(size_t)(bq * DIM + d) * NP + m0 + j4 * 4];
      As[(j4 * 4 + 0) * 132 + d] = v.x;
      As[(j4 * 4 + 1) * 132 + d] = v.y;
      As[(j4 * 4 + 2) * 132 + d] = v.z;
      As[(j4 * 4 + 3) * 132 + d] = v.w;
    }
  }

  float pm[14];
#pragma unroll
  for (int k = 0; k < 14; ++k) pm[k] = 0.f;

  if (trans) {
    const float4* br0 = (const float4*)(f2T + ((size_t)bq * NP + id0) * DIM) + l;
    const float4* br1 = (const float4*)(f2T + ((size_t)bq * NP + id1) * DIM) + l;
    const float4* br2 = (const float4*)(f2T + ((size_t)bq * NP + id2) * DIM) + l;
    const float4* br3 = (const float4*)(f2T + ((size_t)bq * NP + id3) * DIM) + l;
    float4 y00 = br0[0], y01 = br0[8], y02 = br0[16], y03 = br0[24];
    float4 y10 = br1[0], y11 = br1[8], y12 = br1[16], y13 = br1[24];
    const float* xq0 = xyz2 + ((size_t)bq * NP + id0) * 3;
    const float* xq1 = xyz2 + ((size_t)bq * NP + id1) * 3;
    float x0x = xq0[0], x0y = xq0[1], x0z = xq0[2];
    float x1x = xq1[0], x1y = xq1[1], x1z = xq1[2];
    float4 y20 = br2[0], y21 = br2[8], y22 = br2[16], y23 = br2[24];
    float4 y30 = br3[0], y31 = br3[8], y32 = br3[16], y33 = br3[24];
    const float* xq2 = xyz2 + ((size_t)bq * NP + id2) * 3;
    const float* xq3 = xyz2 + ((size_t)bq * NP + id3) * 3;
    float x2x = xq2[0], x2y = xq2[1], x2z = xq2[2];
    float x3x = xq3[0], x3y = xq3[1], x3z = xq3[2];
    size_t fbase = ((size_t)bq * NP + m0) * NS;
    __syncthreads();  // As visible; global loads continue in flight

#define DO_R(r, ya, yb, yc, yd, nxx, nxy, nxz)                                 \
    {                                                                          \
      int pi = (r) * 32 + g;                                                   \
      int m = pi >> 3;                                                         \
      const float4* arow = (const float4*)&As[m * 132] + l;                    \
      float4 a0 = arow[0], a1 = arow[8], a2 = arow[16], a3 = arow[24];         \
      float acc = a0.x * ya.x + a0.y * ya.y + a0.z * ya.z + a0.w * ya.w +      \
                  a1.x * yb.x + a1.y * yb.y + a1.z * yb.z + a1.w * yb.w +      \
                  a2.x * yc.x + a2.y * yc.y + a2.z * yc.z + a2.w * yc.w +      \
                  a3.x * yd.x + a3.y * yd.y + a3.z * yd.z + a3.w * yd.w;       \
      acc += __shfl_xor(acc, 1);                                               \
      acc += __shfl_xor(acc, 2);                                               \
      acc += __shfl_xor(acc, 4);                                               \
      float corr = acc * 0.08838834764831843f;                                 \
      const float* cpq = coords + ((size_t)bq * NP + m0 + m) * 3;              \
      float dx = nxx - cpq[0], dy = nxy - cpq[1], dz = nxz - cpq[2];           \
      if (l == 0) {                                                            \
        float4 fv;                                                             \
        fv.x = corr; fv.y = dx; fv.z = dy; fv.w = dz;                          \
        ((float4*)feat)[fbase + pi] = fv;                                      \
      }                                                                        \
      pm[0] += corr; pm[1] += dx; pm[2] += dy; pm[3] += dz;                    \
      pm[4] += corr * corr; pm[5] += corr * dx; pm[6] += corr * dy;            \
      pm[7] += corr * dz; pm[8] += dx * dx; pm[9] += dx * dy;                  \
      pm[10] += dx * dz; pm[11] += dy * dy; pm[12] += dy * dz;                 \
      pm[13] += dz * dz;                                                       \
    }
    DO_R(0, y00, y01, y02, y03, x0x, x0y, x0z)
    DO_R(1, y10, y11, y12, y13, x1x, x1y, x1z)
    DO_R(2, y20, y21, y22, y23, x2x, x2y, x2z)
    DO_R(3, y30, y31, y32, y33, x3x, x3y, x3z)
#undef DO_R
  } else {
    __syncthreads();
    int idv[4] = {id0, id1, id2, id3};
#pragma unroll
    for (int r = 0; r < 4; ++r) {
      int pi = r * 32 + g;
      int m = pi >> 3, s = pi & 7;
      int id = idv[r];
      float acc = 0.f;
#pragma unroll
      for (int k = 0; k < 4; ++k) {
#pragma unroll
        for (int c = 0; c < 4; ++c) {
          int d = (l + 8 * k) * 4 + c;
          acc += f1[(size_t)(bq * DIM + d) * NP + m0 + m] *
                 f2[(size_t)(bq * DIM + d) * NP + id];
        }
      }
      acc += __shfl_xor(acc, 1);
      acc += __shfl_xor(acc, 2);
      acc += __shfl_xor(acc, 4);
      float corr = acc * 0.08838834764831843f;
      const float* cpq = coords + ((size_t)bq * NP + m0 + m) * 3;
      const float* xp = xyz2 + ((size_t)bq * NP + id) * 3;
      float dx = xp[0] - cpq[0], dy = xp[1] - cpq[1], dz = xp[2] - cpq[2];
      if (l == 0) {
        float4 fv;
        fv.x = corr; fv.y = dx; fv.z = dy; fv.w = dz;
        ((float4*)feat)[((size_t)bq * NP + m0 + m) * NS + s] = fv;
      }
      pm[0] += corr; pm[1] += dx; pm[2] += dy; pm[3] += dz;
      pm[4] += corr * corr; pm[5] += corr * dx; pm[6] += corr * dy;
      pm[7] += corr * dz; pm[8] += dx * dx; pm[9] += dx * dy;
      pm[10] += dx * dz; pm[11] += dy * dy; pm[12] += dy * dz;
      pm[13] += dz * dz;
    }
  }

#pragma unroll
  for (int k = 0; k < 14; ++k) {
    float v = pm[k];
#pragma unroll
    for (int off = 32; off; off >>= 1) v += __shfl_xor(v, off);
    pm[k] = v;
  }
  int lane = t & 63, wvv = t >> 6;
  if (lane == 0) {
#pragma unroll
    for (int k = 0; k < 14; ++k) red[wvv][k] = pm[k];
  }
  __syncthreads();
  if (t < 14) {
    float ssum = (red[0][t] + red[1][t] + red[2][t] + red[3][t]) * 0.125f;
    parts[((size_t)bq * 256 + chunk) * 14 + t] = ssum;
  }
}

// ======== K3: stats + conv+GN+PReLU+max + out GEMM (1024 x 256, proven) =====
__global__ __launch_bounds__(256) void kB_out(
    const float* __restrict__ feat, const float* __restrict__ parts,
    const float* __restrict__ conv_w, const float* __restrict__ conv_b,
    const float* __restrict__ gamma, const float* __restrict__ beta,
    const float* __restrict__ prelu, const float* __restrict__ out_w,
    const float* __restrict__ out_b, float* __restrict__ out) {
  int b = blockIdx.x >> 8;
  int n0 = (blockIdx.x & 255) * 16;
  __shared__ float4 fs4[16 * 8];
  __shared__ float4 vs4[16 * 16];
  __shared__ float4 ow4[64 * 16];
  __shared__ float cw[256], cb_[64], Av[64], Bv[64], ob_[64];
  __shared__ float red2[8][14];
  __shared__ float Sm[14];
  __shared__ float SxA[64], SxxA[64];
  int t = threadIdx.x;
  if (t < 128) fs4[t] = ((const float4*)(feat + ((size_t)b * NP + n0) * 32))[t];
  {
    const float4* src = (const float4*)out_w;
#pragma unroll
    for (int k = 0; k < 4; ++k) {
      int i4 = t + k * 256;
      int oo = i4 >> 4, gg = i4 & 15;
      ow4[oo * 16 + (gg ^ ((oo >> 2) & 7))] = src[i4];
    }
  }
  cw[t] = conv_w[t];
  if (t < 64) {
    cb_[t] = conv_b[t];
    ob_[t] = out_b[t];
  }
  if (t < 112) {
    int k = t % 14, jg = t / 14;
    float s = 0.f;
    const float* pp = parts + ((size_t)b * 256 + jg * 32) * 14 + k;
#pragma unroll 8
    for (int j = 0; j < 32; ++j) s += pp[j * 14];
    red2[jg][k] = s;
  }
  float alpha = prelu[0];
  __syncthreads();
  if (t < 14) {
    float s = 0.f;
#pragma unroll
    for (int jg = 0; jg < 8; ++jg) s += red2[jg][t];
    Sm[t] = s;
  }
  __syncthreads();
  if (t < 64) {
    int o = t;
    float w0 = cw[o * 4 + 0], w1 = cw[o * 4 + 1];
    float w2 = cw[o * 4 + 2], w3 = cw[o * 4 + 3];
    float bo = cb_[o];
    const float cnt = (float)(NP * NS);
    float wS1 = w0 * Sm[0] + w1 * Sm[1] + w2 * Sm[2] + w3 * Sm[3];
    float q = w0 * w0 * Sm[4] + w1 * w1 * Sm[8] + w2 * w2 * Sm[11] +
              w3 * w3 * Sm[13] +
              2.f * (w0 * w1 * Sm[5] + w0 * w2 * Sm[6] + w0 * w3 * Sm[7] +
                     w1 * w2 * Sm[9] + w1 * w3 * Sm[10] + w2 * w3 * Sm[12]);
    SxA[o] = wS1 + bo * cnt;
    SxxA[o] = q + 2.f * bo * wS1 + bo * bo * cnt;
  }
  __syncthreads();
  if (t < 64) {
    int o = t, g = o >> 3;
    const float cnt = (float)(NP * NS);
    float sm = 0.f, s2 = 0.f;
#pragma unroll
    for (int k = 0; k < 8; ++k) {
      sm += SxA[g * 8 + k];
      s2 += SxxA[g * 8 + k];
    }
    float mean = sm / (cnt * 8.f);
    float e2 = s2 / (cnt * 8.f);
    float var = e2 - mean * mean;
    float inv = rsqrtf(var + 1e-5f);
    float A = gamma[o] * inv;
    Av[o] = A;
    Bv[o] = beta[o] - mean * A;
  }
  __syncthreads();
  {
    int o = t & 63;
    int pw = t >> 6;
    float w0 = cw[o * 4 + 0], w1 = cw[o * 4 + 1];
    float w2 = cw[o * 4 + 2], w3 = cw[o * 4 + 3];
    float A = Av[o], Bc = Bv[o], bb = cb_[o];
    float* vsf = (float*)vs4;
#pragma unroll
    for (int i = 0; i < 4; ++i) {
      int p = pw * 4 + i;
      float mx = -INFINITY;
#pragma unroll
      for (int s = 0; s < NS; ++s) {
        float4 f = fs4[p * 8 + s];
        float x = fmaf(w0, f.x, fmaf(w1, f.y, fmaf(w2, f.z, fmaf(w3, f.w, bb))));
        float y = fmaf(A, x, Bc);
        y = (y >= 0.f) ? y : alpha * y;
        mx = fmaxf(mx, y);
      }
      vsf[(p * 16 + ((o >> 2) ^ ((p >> 2) & 7))) * 4 + (o & 3)] = mx;
    }
  }
  __syncthreads();
  {
    int ti = t >> 3;
    int tj = t & 7;
    float acc[2][2];
#pragma unroll
    for (int oi = 0; oi < 2; ++oi)
#pragma unroll
      for (int pj = 0; pj < 2; ++pj) acc[oi][pj] = 0.f;
#pragma unroll
    for (int g = 0; g < 16; ++g) {
      float4 vv[2], ww[2];
#pragma unroll
      for (int pj = 0; pj < 2; ++pj) {
        int p = tj * 2 + pj;
        vv[pj] = vs4[p * 16 + (g ^ ((p >> 2) & 7))];
      }
#pragma unroll
      for (int oi = 0; oi < 2; ++oi) {
        int oo = ti * 2 + oi;
        ww[oi] = ow4[oo * 16 + (g ^ ((oo >> 2) & 7))];
      }
#pragma unroll
      for (int oi = 0; oi < 2; ++oi)
#pragma unroll
        for (int pj = 0; pj < 2; ++pj) {
          acc[oi][pj] = fmaf(ww[oi].x, vv[pj].x, acc[oi][pj]);
          acc[oi][pj] = fmaf(ww[oi].y, vv[pj].y, acc[oi][pj]);
          acc[oi][pj] = fmaf(ww[oi].z, vv[pj].z, acc[oi][pj]);
          acc[oi][pj] = fmaf(ww[oi].w, vv[pj].w, acc[oi][pj]);
        }
    }
#pragma unroll
    for (int oi = 0; oi < 2; ++oi) {
      int oo = ti * 2 + oi;
      float bb = ob_[oo];
      float2 r;
      r.x = acc[oi][0] + bb;
      r.y = acc[oi][1] + bb;
      *(float2*)&out[((size_t)b * CCH + oo) * NP + n0 + tj * 2] = r;
    }
  }
}

extern "C" void kernel_launch(void* const* d_in, const int* in_sizes, int n_in,
                              void* d_out, int out_size, void* d_ws, size_t ws_size,
                              hipStream_t stream) {
  const float* coords = (const float*)d_in[0];
  const float* xyz2 = (const float*)d_in[1];
  const float* fmap1 = (const float*)d_in[2];
  const float* fmap2 = (const float*)d_in[3];
  const float* conv_w = (const float*)d_in[4];
  const float* conv_b = (const float*)d_in[5];
  const float* gamma = (const float*)d_in[6];
  const float* beta = (const float*)d_in[7];
  const float* prelu = (const float*)d_in[8];
  const float* out_w = (const float*)d_in[9];
  const float* out_b = (const float*)d_in[10];
  float* out = (float*)d_out;
  float* ws = (float*)d_ws;

  const size_t BND = (size_t)B * NP * DIM;
  const size_t FEAT = (size_t)B * NP * NS * 4;
  const size_t PARTS = (size_t)B * 256 * 14;
  size_t needT = (BND + FEAT + PARTS + 512) * sizeof(float) +
                 (size_t)B * NP * NS * sizeof(int);
  int useT = (ws_size >= needT) ? 1 : 0;

  float* f2T = ws;
  float* featp = useT ? (f2T + BND) : ws;
  float* parts = featp + FEAT;
  int* idxp = (int*)(parts + PARTS + 512);

  int nblk = B * NP + (useT ? (B * (NP / 32)) : 0);
  kA_bq_transpose<<<dim3(nblk), dim3(256), 0, stream>>>(coords, xyz2, idxp,
                                                        fmap2, f2T);
  k_corrfeat<<<dim3(1024), dim3(256), 0, stream>>>(
      coords, xyz2, fmap1, fmap2, f2T, idxp, featp, parts, useT);
  kB_out<<<dim3(B * (NP / 16)), dim3(256), 0, stream>>>(
      featp, parts, conv_w, conv_b, gamma, beta, prelu, out_w, out_b, out);
}